// Round 7
// baseline (49.744 us; speedup 1.0000x reference)
//
#include <hip/hip_runtime.h>

typedef unsigned short ushort8v __attribute__((ext_vector_type(8)));
typedef float float4v __attribute__((ext_vector_type(4)));

namespace {
constexpr int kB = 2, kC = 256, kH = 100, kW = 152;
constexpr int kN = 1000;
constexpr int kPH = 7, kPW = 7, kSR = 2;
constexpr float kScale = 0.0625f;
constexpr int kHW = kH * kW;                 // 15200
constexpr int kWC = kW * kC;                 // row stride in elems
constexpr int kBins = kPH * kPW;             // 49
constexpr int kOutPerRoi = kC * kBins;       // 12544
constexpr int kStrideE = 260;                // bf16 elems; 130 u32 words
constexpr int kThreads = 512;
}

__device__ __forceinline__ float b2f(unsigned short u) {
  union { unsigned int i; float f; } x; x.i = ((unsigned int)u) << 16; return x.f;
}
__device__ __forceinline__ unsigned short f2b(float f) {
  union { float f; unsigned int i; } x; x.f = f;
  return (unsigned short)((x.i + 0x7FFFu + ((x.i >> 16) & 1u)) >> 16);  // RNE
}

// (B,C,H,W) f32 -> (B,H*W,C) bf16, tiled 32x32 transpose
__global__ __launch_bounds__(256) void transpose_k(const float* __restrict__ in,
                                                   unsigned short* __restrict__ out) {
  __shared__ float tile[32][33];
  const int b = blockIdx.z;
  const int hw0 = blockIdx.x * 32;
  const int c0 = blockIdx.y * 32;
  const int tx = threadIdx.x;   // 0..7  (x4 floats)
  const int ty = threadIdx.y;   // 0..31
  const float4v v = __builtin_nontemporal_load(
      (const float4v*)(in + (size_t)b * kC * kHW + (size_t)(c0 + ty) * kHW + hw0 + tx * 4));
  tile[tx * 4 + 0][ty] = v.x;
  tile[tx * 4 + 1][ty] = v.y;
  tile[tx * 4 + 2][ty] = v.z;
  tile[tx * 4 + 3][ty] = v.w;
  __syncthreads();
  unsigned int lo = (unsigned int)f2b(tile[ty][tx * 4 + 0]) |
                    ((unsigned int)f2b(tile[ty][tx * 4 + 1]) << 16);
  unsigned int hi = (unsigned int)f2b(tile[ty][tx * 4 + 2]) |
                    ((unsigned int)f2b(tile[ty][tx * 4 + 3]) << 16);
  unsigned int* dst = (unsigned int*)(out + (size_t)b * kHW * kC +
                                      (size_t)(hw0 + ty) * kC + c0 + tx * 4);
  dst[0] = lo;
  dst[1] = hi;
}

// one block per ROI; 8 waves; per-bin duplicate rows/cols merged into weights.
// lanes 0-31 = first col of a pair, 32-63 = second; lane covers 8 channels.
__global__ __launch_bounds__(kThreads, 8) void roialign_k(
    const unsigned short* __restrict__ ft, const float* __restrict__ rois,
    float* __restrict__ out) {
  __shared__ unsigned short sOut[kBins * kStrideE];  // ~24.9 KB
  __shared__ int sNy[kPH], sYoff[kPH][4];            // row offsets (elems), count
  __shared__ float sWy[kPH][4];
  __shared__ int sNx[kPW], sXoff[kPW][2];            // col-pair start offsets (elems)
  __shared__ float sWx[kPW][2][2];                   // [pw][load][half]
  __shared__ int sB;

  const int n = blockIdx.x;
  const int t = threadIdx.x;

  // 14 threads: t<7 -> y-merge for ph=t; t in [7,14) -> x-merge for pw=t-7
  if (t < kPH + kPW) {
    const bool isX = t >= kPH;
    const int p = isX ? t - kPH : t;
    const float a1 = rois[n * 5 + (isX ? 1 : 2)] * kScale;
    const float a2 = rois[n * 5 + (isX ? 3 : 4)] * kScale;
    const float span = fmaxf(a2 - a1, 1.0f);
    const float binsz = span / (isX ? kPW : kPH);
    const float size = isX ? (float)kW : (float)kH;
    int lo_i[2]; float wh[2], wl[2];
#pragma unroll
    for (int s = 0; s < 2; ++s) {
      const float c = a1 + p * binsz + (s + 0.5f) * binsz / kSR;
      const bool valid = (c > -1.0f) && (c < size);
      const float cc = fminf(fmaxf(c, 0.0f), size - 1.0f);
      const float lo = fminf(floorf(cc), size - 2.0f);
      const float fr = cc - lo;
      lo_i[s] = (int)lo;
      wh[s] = valid ? (1.0f - fr) * 0.5f : 0.0f;  // 0.5 = folded 1/SR avg
      wl[s] = valid ? fr * 0.5f : 0.0f;
    }
    const int d = lo_i[1] - lo_i[0];
    if (!isX) {
      int nrow; int rows[4]; float w[4];
      if (d == 0)      { nrow = 2; rows[0]=lo_i[0]; rows[1]=lo_i[0]+1;
                         w[0]=wh[0]+wh[1]; w[1]=wl[0]+wl[1]; rows[2]=rows[3]=rows[1]; w[2]=w[3]=0.f; }
      else if (d == 1) { nrow = 3; rows[0]=lo_i[0]; rows[1]=lo_i[0]+1; rows[2]=lo_i[0]+2;
                         w[0]=wh[0]; w[1]=wl[0]+wh[1]; w[2]=wl[1]; rows[3]=rows[2]; w[3]=0.f; }
      else             { nrow = 4; rows[0]=lo_i[0]; rows[1]=lo_i[0]+1; rows[2]=lo_i[1]; rows[3]=lo_i[1]+1;
                         w[0]=wh[0]; w[1]=wl[0]; w[2]=wh[1]; w[3]=wl[1]; }
      sNy[p] = nrow;
#pragma unroll
      for (int i = 0; i < 4; ++i) { sYoff[p][i] = rows[i] * kWC; sWy[p][i] = w[i]; }
    } else {
      if (d == 0) {
        sNx[p] = 1;
        sXoff[p][0] = lo_i[0] * kC; sWx[p][0][0] = wh[0]+wh[1]; sWx[p][0][1] = wl[0]+wl[1];
        sXoff[p][1] = lo_i[0] * kC; sWx[p][1][0] = 0.f; sWx[p][1][1] = 0.f;
      } else if (d == 1) {
        sNx[p] = 2;
        sXoff[p][0] = lo_i[0] * kC;       sWx[p][0][0] = wh[0]; sWx[p][0][1] = wl[0]+wh[1];
        sXoff[p][1] = (lo_i[0] + 2) * kC; sWx[p][1][0] = wl[1]; sWx[p][1][1] = 0.f;
      } else {
        sNx[p] = 2;
        sXoff[p][0] = lo_i[0] * kC; sWx[p][0][0] = wh[0]; sWx[p][0][1] = wl[0];
        sXoff[p][1] = lo_i[1] * kC; sWx[p][1][0] = wh[1]; sWx[p][1][1] = wl[1];
      }
    }
  }
  if (t == 0) sB = (int)rois[n * 5 + 0];
  __syncthreads();

  const int wave = t >> 6;       // 0..7
  const int lane = t & 63;
  const int half = lane >> 5;    // which column of a pair
  const int sub = lane & 31;     // channel octet index
  const unsigned short* fbh = ft + (size_t)sB * kHW * kC + half * kC + sub * 8;
  unsigned int* s32 = (unsigned int*)sOut;

  for (int bin = wave; bin < kBins; bin += 8) {
    const int ph = bin / kPW, pw = bin - (bin / kPW) * kPW;
    const int ny = sNy[ph], nx = sNx[pw];
    const int xo0 = sXoff[pw][0], xo1 = sXoff[pw][1];
    const float wx0 = sWx[pw][0][half], wx1 = sWx[pw][1][half];
    float acc[8] = {0.f, 0.f, 0.f, 0.f, 0.f, 0.f, 0.f, 0.f};
#pragma unroll 4
    for (int r = 0; r < ny; ++r) {
      const float wy = sWy[ph][r];
      const int ro = sYoff[ph][r];
      {
        const float w = wy * wx0;
        const ushort8v v = *(const ushort8v*)(fbh + ro + xo0);
#pragma unroll
        for (int k = 0; k < 8; ++k) acc[k] += w * b2f(v[k]);
      }
      if (nx == 2) {
        const float w = wy * wx1;
        const ushort8v v = *(const ushort8v*)(fbh + ro + xo1);
#pragma unroll
        for (int k = 0; k < 8; ++k) acc[k] += w * b2f(v[k]);
      }
    }
    // merge the two column-halves: butterfly across lane^32
#pragma unroll
    for (int k = 0; k < 8; ++k) acc[k] += __shfl_xor(acc[k], 32);
    const int kBase = half * 4;
    const unsigned int wA = (unsigned int)f2b(acc[kBase + 0]) |
                            ((unsigned int)f2b(acc[kBase + 1]) << 16);
    const unsigned int wB = (unsigned int)f2b(acc[kBase + 2]) |
                            ((unsigned int)f2b(acc[kBase + 3]) << 16);
    const int wIdx = bin * (kStrideE / 2) + sub * 4 + half * 2;
    s32[wIdx + 0] = wA;
    s32[wIdx + 1] = wB;
  }
  __syncthreads();

  // coalesced float4 non-temporal write of this ROI's (C,PH,PW) block
  float4v* ob4 = (float4v*)(out + (size_t)n * kOutPerRoi);
  for (int q = t; q < kOutPerRoi / 4; q += kThreads) {
    const int f = q * 4;
    const int c0 = (f + 0) / kBins, b0 = (f + 0) - c0 * kBins;
    const int c1 = (f + 1) / kBins, b1 = (f + 1) - c1 * kBins;
    const int c2 = (f + 2) / kBins, b2 = (f + 2) - c2 * kBins;
    const int c3 = (f + 3) / kBins, b3 = (f + 3) - c3 * kBins;
    float4v v;
    v.x = b2f(sOut[b0 * kStrideE + c0]);
    v.y = b2f(sOut[b1 * kStrideE + c1]);
    v.z = b2f(sOut[b2 * kStrideE + c2]);
    v.w = b2f(sOut[b3 * kStrideE + c3]);
    __builtin_nontemporal_store(v, &ob4[q]);
  }
}

extern "C" void kernel_launch(void* const* d_in, const int* in_sizes, int n_in,
                              void* d_out, int out_size, void* d_ws, size_t ws_size,
                              hipStream_t stream) {
  const float* feat = (const float*)d_in[0];
  const float* rois = (const float*)d_in[1];
  float* out = (float*)d_out;
  unsigned short* ft = (unsigned short*)d_ws;  // kB*kHW*kC*2 = 15.6 MB scratch

  hipLaunchKernelGGL(transpose_k, dim3(kHW / 32, kC / 32, kB), dim3(8, 32), 0,
                     stream, feat, ft);
  hipLaunchKernelGGL(roialign_k, dim3(kN), dim3(kThreads), 0, stream, ft, rois, out);
}

// Round 8
// 42.829 us; speedup vs baseline: 1.1615x; 1.1615x over previous
//
#include <hip/hip_runtime.h>

typedef unsigned short ushort8v __attribute__((ext_vector_type(8)));
typedef float float4v __attribute__((ext_vector_type(4)));

namespace {
constexpr int kB = 2, kC = 256, kH = 100, kW = 152;
constexpr int kN = 1000;
constexpr int kPH = 7, kPW = 7, kSR = 2;
constexpr float kScale = 0.0625f;
constexpr int kHW = kH * kW;                 // 15200
constexpr int kBins = kPH * kPW;             // 49
constexpr int kOutPerRoi = kC * kBins;       // 12544
constexpr int kStrideE = 260;                // bf16 elems; 130 u32 words
constexpr int kNY = kPH * kSR;               // 14
constexpr int kNX = kPW * kSR;               // 14
constexpr int kThreads = 512;
}

__device__ __forceinline__ float b2f(unsigned short u) {
  union { unsigned int i; float f; } x; x.i = ((unsigned int)u) << 16; return x.f;
}
__device__ __forceinline__ unsigned short f2b(float f) {
  union { float f; unsigned int i; } x; x.f = f;
  return (unsigned short)((x.i + 0x7FFFu + ((x.i >> 16) & 1u)) >> 16);  // RNE
}

// (B,C,H,W) f32 -> (B,H*W,C) bf16, tiled 32x32 transpose
__global__ __launch_bounds__(256) void transpose_k(const float* __restrict__ in,
                                                   unsigned short* __restrict__ out) {
  __shared__ float tile[32][33];
  const int b = blockIdx.z;
  const int hw0 = blockIdx.x * 32;
  const int c0 = blockIdx.y * 32;
  const int tx = threadIdx.x;   // 0..7  (x4 floats)
  const int ty = threadIdx.y;   // 0..31
  const float4 v = *(const float4*)(in + (size_t)b * kC * kHW +
                                    (size_t)(c0 + ty) * kHW + hw0 + tx * 4);
  tile[tx * 4 + 0][ty] = v.x;
  tile[tx * 4 + 1][ty] = v.y;
  tile[tx * 4 + 2][ty] = v.z;
  tile[tx * 4 + 3][ty] = v.w;
  __syncthreads();
  unsigned int lo = (unsigned int)f2b(tile[ty][tx * 4 + 0]) |
                    ((unsigned int)f2b(tile[ty][tx * 4 + 1]) << 16);
  unsigned int hi = (unsigned int)f2b(tile[ty][tx * 4 + 2]) |
                    ((unsigned int)f2b(tile[ty][tx * 4 + 3]) << 16);
  unsigned int* dst = (unsigned int*)(out + (size_t)b * kHW * kC +
                                      (size_t)(hw0 + ty) * kC + c0 + tx * 4);
  dst[0] = lo;
  dst[1] = hi;
}

// one block per ROI; 8 waves; per bin: lanes 0-31 = x-lo corner, 32-63 = x-hi,
// each lane 8 channels via one 16B load -> 1KB contiguous per wave instruction
__global__ __launch_bounds__(kThreads, 8) void roialign_k(
    const unsigned short* __restrict__ ft, const float* __restrict__ rois,
    float* __restrict__ out) {
  __shared__ unsigned short sOut[kBins * kStrideE];  // ~24.9 KB
  __shared__ int sYlo[kNY], sXlo[kNX];
  __shared__ float sHy[kNY], sLy[kNY], sHx[kNX], sLx[kNX];
  __shared__ int sB;

  const int n = blockIdx.x;
  const int t = threadIdx.x;

  if (t < kNY + kNX) {
    const bool isX = t >= kNY;
    const int i = isX ? t - kNY : t;
    const float x1 = rois[n * 5 + 1] * kScale;
    const float y1 = rois[n * 5 + 2] * kScale;
    const float x2 = rois[n * 5 + 3] * kScale;
    const float y2 = rois[n * 5 + 4] * kScale;
    const float roiw = fmaxf(x2 - x1, 1.0f);
    const float roih = fmaxf(y2 - y1, 1.0f);
    const float start = isX ? x1 : y1;
    const float binsz = isX ? (roiw / kPW) : (roih / kPH);
    const float size = isX ? (float)kW : (float)kH;
    const int p = i / kSR, s = i % kSR;
    const float c = start + p * binsz + (s + 0.5f) * binsz / kSR;
    const bool valid = (c > -1.0f) && (c < size);
    const float cc = fminf(fmaxf(c, 0.0f), size - 1.0f);
    const float lo = fminf(floorf(cc), size - 2.0f);
    const float fr = cc - lo;
    // fold the 1/(SR*SR)=0.25 average into the weights (0.5 per axis)
    const float wHi = valid ? (1.0f - fr) * 0.5f : 0.0f;
    const float wLo = valid ? fr * 0.5f : 0.0f;
    if (isX) { sXlo[i] = (int)lo; sHx[i] = wHi; sLx[i] = wLo; }
    else     { sYlo[i] = (int)lo; sHy[i] = wHi; sLy[i] = wLo; }
  }
  if (t == 0) sB = (int)rois[n * 5 + 0];
  __syncthreads();

  const int wave = t >> 6;       // 0..7
  const int lane = t & 63;
  const int half = lane >> 5;    // 0: x-lo corner, 1: x-hi corner
  const int sub = lane & 31;     // channel octet index
  const unsigned short* fb = ft + (size_t)sB * kHW * kC + sub * 8;
  unsigned int* s32 = (unsigned int*)sOut;

  for (int bin = wave; bin < kBins; bin += 8) {
    const int ph = bin / kPW, pw = bin % kPW;
    float acc[8] = {0.f, 0.f, 0.f, 0.f, 0.f, 0.f, 0.f, 0.f};
#pragma unroll
    for (int sy = 0; sy < kSR; ++sy) {
      const int iy = ph * kSR + sy;
      const int ylo = sYlo[iy];
      const float hy = sHy[iy], ly = sLy[iy];
#pragma unroll
      for (int sx = 0; sx < kSR; ++sx) {
        const int ix = pw * kSR + sx;
        const int xlo = sXlo[ix];
        const float hxs = half ? sLx[ix] : sHx[ix];   // this half's x-weight
        const float wTop = hy * hxs, wBot = ly * hxs;
        const unsigned short* p0 = fb + ((size_t)(ylo * kW + xlo + half)) * kC;
        const ushort8v v0 = *(const ushort8v*)(p0);            // row ylo
        const ushort8v v1 = *(const ushort8v*)(p0 + kW * kC);  // row ylo+1
#pragma unroll
        for (int k = 0; k < 8; ++k)
          acc[k] += wTop * b2f(v0[k]) + wBot * b2f(v1[k]);
      }
    }
    // merge the two corner-halves: butterfly across lane^32
#pragma unroll
    for (int k = 0; k < 8; ++k) acc[k] += __shfl_xor(acc[k], 32);
    // lane stores 2 u32 words (4 channels), picked by half; 8B-aligned
    const int kBase = half * 4;
    const unsigned int wA = (unsigned int)f2b(acc[kBase + 0]) |
                            ((unsigned int)f2b(acc[kBase + 1]) << 16);
    const unsigned int wB = (unsigned int)f2b(acc[kBase + 2]) |
                            ((unsigned int)f2b(acc[kBase + 3]) << 16);
    const int wIdx = bin * (kStrideE / 2) + sub * 4 + half * 2;
    s32[wIdx + 0] = wA;
    s32[wIdx + 1] = wB;
  }
  __syncthreads();

  // coalesced non-temporal float4 write of this ROI's (C,PH,PW) block
  float4v* ob4 = (float4v*)(out + (size_t)n * kOutPerRoi);
  for (int q = t; q < kOutPerRoi / 4; q += kThreads) {
    const int f = q * 4;
    const int c0 = (f + 0) / kBins, b0 = (f + 0) - c0 * kBins;
    const int c1 = (f + 1) / kBins, b1 = (f + 1) - c1 * kBins;
    const int c2 = (f + 2) / kBins, b2 = (f + 2) - c2 * kBins;
    const int c3 = (f + 3) / kBins, b3 = (f + 3) - c3 * kBins;
    float4v v;
    v.x = b2f(sOut[b0 * kStrideE + c0]);
    v.y = b2f(sOut[b1 * kStrideE + c1]);
    v.z = b2f(sOut[b2 * kStrideE + c2]);
    v.w = b2f(sOut[b3 * kStrideE + c3]);
    __builtin_nontemporal_store(v, &ob4[q]);
  }
}

extern "C" void kernel_launch(void* const* d_in, const int* in_sizes, int n_in,
                              void* d_out, int out_size, void* d_ws, size_t ws_size,
                              hipStream_t stream) {
  const float* feat = (const float*)d_in[0];
  const float* rois = (const float*)d_in[1];
  float* out = (float*)d_out;
  unsigned short* ft = (unsigned short*)d_ws;  // kB*kHW*kC*2 = 15.6 MB scratch

  hipLaunchKernelGGL(transpose_k, dim3(kHW / 32, kC / 32, kB), dim3(8, 32), 0,
                     stream, feat, ft);
  hipLaunchKernelGGL(roialign_k, dim3(kN), dim3(kThreads), 0, stream, ft, rois, out);
}